// Round 16
// baseline (1380.535 us; speedup 1.0000x reference)
//
#include <hip/hip_runtime.h>
#include <math.h>

#define T_TOK 16384
#define D_IN  1024
#define D_H   4096
#define GQ    64
#define R_L   32
#define NPANEL 4
#define PANW   (D_H / NPANEL)   // 1024 fc1-output cols per panel

typedef __attribute__((ext_vector_type(8))) __bf16 bf16x8;
typedef __attribute__((ext_vector_type(4))) float  f32x4;
typedef __attribute__((ext_vector_type(8))) unsigned short ushort8;

__device__ __forceinline__ unsigned short f2bf(float f) {
  union { float f; unsigned u; } v; v.f = f;
  unsigned u = v.u + 0x7FFFu + ((v.u >> 16) & 1u);
  return (unsigned short)(u >> 16);
}

__device__ __forceinline__ float bf2f(unsigned short h) {
  union { unsigned u; float f; } v; v.u = ((unsigned)h) << 16; return v.f;
}

__device__ __forceinline__ void gload_lds16(const unsigned short* g, unsigned short* l) {
  __builtin_amdgcn_global_load_lds(
      (const __attribute__((address_space(1))) unsigned int*)g,
      (__attribute__((address_space(3))) unsigned int*)l, 16, 0, 0);
}

// f32 tanh-GELU (h-path errors ~1e-7 only hit the cheap fc2 quantizer)
__device__ __forceinline__ float gelu_tanh(float v) {
  float u = 0.7978845608028654f * (v + 0.044715f * v * v * v);
  return 0.5f * v * (1.0f + tanhf(u));
}

// ---------------- K0: int4 weights -> bf16 (exact) ----------------
__global__ __launch_bounds__(256)
void convert_kernel(const int* __restrict__ qw1, const int* __restrict__ qw2,
                    unsigned short* __restrict__ qw1b, unsigned short* __restrict__ qw2b) {
  const size_t N1 = (size_t)D_H * D_IN;
  const size_t N2 = (size_t)D_IN * D_H;
  const size_t total = N1 + N2;
  for (size_t i = (size_t)blockIdx.x * 256 + threadIdx.x; i < total;
       i += (size_t)gridDim.x * 256) {
    if (i < N1) qw1b[i]    = f2bf((float)qw1[i]);
    else        qw2b[i-N1] = f2bf((float)qw2[i-N1]);
  }
}

// ---------------- K1: fc1 qdq in f64 (decisions MUST match f64 ref) ----------------
__global__ __launch_bounds__(256)
void prep1_kernel(const float* __restrict__ x, const float* __restrict__ smooth,
                  const float* __restrict__ ld,
                  unsigned short* __restrict__ qx, float* __restrict__ sx,
                  float* __restrict__ xrf) {
  __shared__ float xrow[D_IN];
  const int t = blockIdx.x;
  const int tid = threadIdx.x;
  float4 x4  = *(const float4*)(x + (size_t)t * D_IN + tid * 4);
  float4 sm4 = *(const float4*)(smooth + tid * 4);
  *(float4*)&xrow[tid * 4] = x4;
  // f64 quantizer decisions (bit-faithful to the f64 numpy reference);
  // flips here cascade (~0.05-0.4 absmax each) -> keep f64.
  double z0 = (double)x4.x / (double)sm4.x;
  double z1 = (double)x4.y / (double)sm4.y;
  double z2 = (double)x4.z / (double)sm4.z;
  double z3 = (double)x4.w / (double)sm4.w;
  double amax = fmax(fmax(fabs(z0), fabs(z1)), fmax(fabs(z2), fabs(z3)));
#pragma unroll
  for (int d = 1; d < 16; d <<= 1) amax = fmax(amax, __shfl_xor(amax, d, 16));
  double s = fmax(amax, 1e-6) / 7.0;
  double q0 = fmin(fmax(rint(z0 / s), -8.0), 7.0);
  double q1 = fmin(fmax(rint(z1 / s), -8.0), 7.0);
  double q2 = fmin(fmax(rint(z2 / s), -8.0), 7.0);
  double q3 = fmin(fmax(rint(z3 / s), -8.0), 7.0);
  ushort4 qu; qu.x = f2bf((float)q0); qu.y = f2bf((float)q1);
  qu.z = f2bf((float)q2); qu.w = f2bf((float)q3);
  *(ushort4*)(qx + (size_t)t * D_IN + tid * 4) = qu;
  if ((tid & 15) == 0) sx[(size_t)t * (D_IN / GQ) + (tid >> 4)] = (float)s;
  __syncthreads();
  // LoRA-down dot in f32: feeds the h-path only (budget 1e-4; f32 gives ~1e-6)
  const int w = tid >> 6, l = tid & 63;
#pragma unroll
  for (int rr = 0; rr < 8; ++rr) {
    int r = w * 8 + rr;
    const float* ldr = ld + (size_t)r * D_IN;
    float sum = 0.f;
#pragma unroll
    for (int k = 0; k < 16; ++k)
      sum = fmaf(xrow[l + 64 * k], ldr[l + 64 * k], sum);
#pragma unroll
    for (int d = 32; d >= 1; d >>= 1) sum += __shfl_xor(sum, d, 64);
    if (l == 0) xrf[(size_t)t * R_L + r] = sum;
  }
}

// ---------------- FC1: MFMA integer main + f32 scale-accumulate + f32 epilogue ----
__global__ __launch_bounds__(512, 2)
void gemm_fc1(const unsigned short* __restrict__ Aq,    // [T][1024] bf16 q
              const float* __restrict__ Asx,            // [T][16] f32
              const unsigned short* __restrict__ Bq,    // [4096][1024] bf16 q
              const float* __restrict__ Bws,            // [4096][16] f32
              const float* __restrict__ xrf,            // [T][32] f32
              const float* __restrict__ lu1,            // [4096][32] f32 raw
              const float* __restrict__ b1,             // [4096]
              const float* __restrict__ smooth2,        // [4096]
              int c0base,
              unsigned short* __restrict__ hb,          // [T][PANW] bf16
              unsigned short* __restrict__ qx2,         // [T][PANW] bf16
              float* __restrict__ sx2) {                // [T][16] f32 panel-local
  __shared__ unsigned short As[2][128 * 64];
  __shared__ unsigned short Bs[2][128 * 64];
  __shared__ float sxd[2][128];
  __shared__ float wss[2][128];
  const int tid = threadIdx.x;     // 0..511
  const int lane = tid & 63;
  const int wid = tid >> 6;        // 0..7
  const int wr = wid >> 1;         // 0..3 (M: 32-row strips)
  const int wc = wid & 1;          // 0..1 (N: 64-col strips)
  const int l15 = lane & 15, l4 = lane >> 4;
  // T1: bijective XCD-chunked remap (nwg = 8*128 = 1024, lin%8 ~ XCD id)
  const int lin = blockIdx.y * 8 + blockIdx.x;
  const int sw  = (lin & 7) * 128 + (lin >> 3);
  const int t0 = (sw >> 3) * 128;
  const int c0 = c0base + (sw & 7) * 128;

  float acc[2][4][4] = {};         // [m][n][j]
  const int srow = tid >> 3;                   // 0..63
  const int schk = tid & 7;                    // dest chunk 0..7
  const int ske  = schk * 8;                   // dest offset (shorts)
  const int sswz = (schk ^ (srow & 7)) * 8;    // source offset (shorts)

  // prologue: stage group 0 + scales 0
#pragma unroll
  for (int q = 0; q < 2; ++q) {
    int row = q * 64 + srow;
    gload_lds16(Aq + (long)(t0 + row) * D_IN + sswz, &As[0][row * 64 + ske]);
    gload_lds16(Bq + (long)(c0 + row) * D_IN + sswz, &Bs[0][row * 64 + ske]);
  }
  if (tid < 128)      sxd[0][tid] = Asx[(long)(t0 + tid) * 16 + 0];
  else if (tid < 256) wss[0][tid - 128] = Bws[(long)(c0 + tid - 128) * 16 + 0];

  int cur = 0;
  for (int g = 0; g < 16; ++g) {
    __syncthreads();   // vmcnt(0)+lgkmcnt(0): stage(g) tiles + scales visible

    if (g < 15) {      // stage g+1 (tiles + scales) into the other buffer
      const int kn = (g + 1) * 64;
      const int nb = cur ^ 1;
#pragma unroll
      for (int q = 0; q < 2; ++q) {
        int row = q * 64 + srow;
        gload_lds16(Aq + (long)(t0 + row) * D_IN + kn + sswz,
                    &As[nb][row * 64 + ske]);
        gload_lds16(Bq + (long)(c0 + row) * D_IN + kn + sswz,
                    &Bs[nb][row * 64 + ske]);
      }
      if (tid < 128)      sxd[nb][tid] = Asx[(long)(t0 + tid) * 16 + (g + 1)];
      else if (tid < 256) wss[nb][tid - 128] = Bws[(long)(c0 + tid - 128) * 16 + (g + 1)];
    }

    float sd[2][4];
#pragma unroll
    for (int m = 0; m < 2; ++m)
#pragma unroll
      for (int jj = 0; jj < 4; ++jj)
        sd[m][jj] = sxd[cur][wr * 32 + m * 16 + l4 * 4 + jj];
    float wd[4];
#pragma unroll
    for (int n = 0; n < 4; ++n)
      wd[n] = wss[cur][wc * 64 + n * 16 + l15];

    bf16x8 af[2][2], bfr[4][2];
#pragma unroll
    for (int m = 0; m < 2; ++m) {
      const int r = wr * 32 + m * 16 + l15;
      const unsigned short* base = &As[cur][r * 64];
      af[m][0] = *(const bf16x8*)(base + ((l4    ) ^ (r & 7)) * 8);
      af[m][1] = *(const bf16x8*)(base + ((l4 + 4) ^ (r & 7)) * 8);
    }
#pragma unroll
    for (int n = 0; n < 4; ++n) {
      const int r = wc * 64 + n * 16 + l15;
      const unsigned short* base = &Bs[cur][r * 64];
      bfr[n][0] = *(const bf16x8*)(base + ((l4    ) ^ (r & 7)) * 8);
      bfr[n][1] = *(const bf16x8*)(base + ((l4 + 4) ^ (r & 7)) * 8);
    }

#pragma unroll
    for (int m = 0; m < 2; ++m) {
#pragma unroll
      for (int n = 0; n < 4; ++n) {
        f32x4 t = {0.f, 0.f, 0.f, 0.f};   // exact integer group-sum (|I|<=4096)
        t = __builtin_amdgcn_mfma_f32_16x16x32_bf16(af[m][0], bfr[n][0], t, 0, 0, 0);
        t = __builtin_amdgcn_mfma_f32_16x16x32_bf16(af[m][1], bfr[n][1], t, 0, 0, 0);
#pragma unroll
        for (int j = 0; j < 4; ++j)
          acc[m][n][j] = fmaf(t[j], sd[m][j] * wd[n], acc[m][n][j]);
      }
    }
    cur ^= 1;
  }

  // ---- stage epilogue operands into reused LDS (stride 36: 16B-aligned, 2-way max) ----
  __syncthreads();                      // everyone done with As/Bs
  float* xr_lds = (float*)&As[0][0];    // [128][36] f32
  float* lu_lds = (float*)&Bs[0][0];    // [128][36] f32
  {
    const int row = tid >> 2;           // 0..127
    const int q4  = (tid & 3) * 8;      // 0,8,16,24
    const float4 a0 = *(const float4*)(xrf + (size_t)(t0 + row) * R_L + q4);
    const float4 a1 = *(const float4*)(xrf + (size_t)(t0 + row) * R_L + q4 + 4);
    *(float4*)&xr_lds[row * 36 + q4]     = a0;
    *(float4*)&xr_lds[row * 36 + q4 + 4] = a1;
    const float4 b0 = *(const float4*)(lu1 + (size_t)(c0 + row) * R_L + q4);
    const float4 b1v = *(const float4*)(lu1 + (size_t)(c0 + row) * R_L + q4 + 4);
    *(float4*)&lu_lds[row * 36 + q4]     = b0;
    *(float4*)&lu_lds[row * 36 + q4 + 4] = b1v;
  }
  __syncthreads();

  // ---- f32 epilogue: lora1 (LDS-fed dot) + b1 + gelu + f32 qdq ----
  float bv[4], rsmv[4];
  int colL[4];
#pragma unroll
  for (int n = 0; n < 4; ++n) {
    int col = c0 + wc * 64 + n * 16 + l15;
    colL[n] = wc * 64 + n * 16 + l15;
    bv[n] = b1[col];
    rsmv[n] = 1.0f / smooth2[col];
  }
  const int clocal0 = c0 - c0base;

#pragma unroll
  for (int m = 0; m < 2; ++m) {
#pragma unroll
    for (int j = 0; j < 4; ++j) {
      const int rloc = wr * 32 + m * 16 + l4 * 4 + j;
      const int trow = t0 + rloc;
      float lor[4] = {0.f, 0.f, 0.f, 0.f};
#pragma unroll
      for (int k = 0; k < 8; ++k) {
        const float4 xq = *(const float4*)&xr_lds[rloc * 36 + k * 4];
#pragma unroll
        for (int n = 0; n < 4; ++n) {
          const float4 lc = *(const float4*)&lu_lds[colL[n] * 36 + k * 4];
          lor[n] = fmaf(xq.x, lc.x, lor[n]);
          lor[n] = fmaf(xq.y, lc.y, lor[n]);
          lor[n] = fmaf(xq.z, lc.z, lor[n]);
          lor[n] = fmaf(xq.w, lc.w, lor[n]);
        }
      }
      float hv[4], z[4];
      float amax = 0.f;
#pragma unroll
      for (int n = 0; n < 4; ++n) {
        float v = acc[m][n][j] + lor[n] + bv[n];
        v = gelu_tanh(v);
        hv[n] = v;
        z[n] = v * rsmv[n];
        amax = fmaxf(amax, fabsf(z[n]));
      }
#pragma unroll
      for (int d = 1; d < 16; d <<= 1) amax = fmaxf(amax, __shfl_xor(amax, d, 16));
      float s = fmaxf(amax, 1e-6f) / 7.0f;
      float rs = 1.0f / s;
#pragma unroll
      for (int n = 0; n < 4; ++n) {
        int coll = clocal0 + wc * 64 + n * 16 + l15;
        hb[(size_t)trow * PANW + coll] = f2bf(hv[n]);
        float qv = fminf(fmaxf(rintf(z[n] * rs), -8.f), 7.f);
        qx2[(size_t)trow * PANW + coll] = f2bf(qv);
      }
      if (l15 == 0)
        sx2[(size_t)trow * (PANW / GQ) + ((clocal0 + wc * 64) >> 6)] = s;
    }
  }
}

// ---------------- FC2: 512-thread mirror of fc1 (T1+T2+dbuf); last pass fuses
//                  +Yprev + b2 + lora2 (xr2a complete by stream order) ----------
__global__ __launch_bounds__(512, 2)
void gemm_fc2(const unsigned short* __restrict__ Aq,    // [T][PANW] bf16 q
              const float* __restrict__ Asx,            // [T][16] f32
              const unsigned short* __restrict__ Bq,    // [1024][4096] bf16 q
              int kB0,
              const float* __restrict__ Bws,            // [1024][64] f32
              int gB0,
              const float* __restrict__ xr2a,           // [T][32] f32 (last pass)
              const float* __restrict__ lu2,            // [1024][32] f32 (last pass)
              const float* __restrict__ b2,             // [1024]   (last pass)
              float* __restrict__ Yout, int first, int last) {
  __shared__ unsigned short As[2][128 * 64];
  __shared__ unsigned short Bs[2][128 * 64];
  __shared__ float sxd[2][128];
  __shared__ float wss[2][128];
  const int tid = threadIdx.x;
  const int lane = tid & 63;
  const int wid = tid >> 6;
  const int wr = wid >> 1;         // 0..3
  const int wc = wid & 1;          // 0..1
  const int l15 = lane & 15, l4 = lane >> 4;
  const int lin = blockIdx.y * 8 + blockIdx.x;
  const int sw  = (lin & 7) * 128 + (lin >> 3);
  const int t0 = (sw >> 3) * 128;
  const int c0 = (sw & 7) * 128;

  float acc[2][4][4] = {};
  const int srow = tid >> 3;
  const int schk = tid & 7;
  const int ske  = schk * 8;
  const int sswz = (schk ^ (srow & 7)) * 8;

#pragma unroll
  for (int q = 0; q < 2; ++q) {
    int row = q * 64 + srow;
    gload_lds16(Aq + (long)(t0 + row) * PANW + sswz, &As[0][row * 64 + ske]);
    gload_lds16(Bq + (long)(c0 + row) * D_H + kB0 + sswz, &Bs[0][row * 64 + ske]);
  }
  if (tid < 128)      sxd[0][tid] = Asx[(long)(t0 + tid) * (PANW / GQ) + 0];
  else if (tid < 256) wss[0][tid - 128] = Bws[(long)(c0 + tid - 128) * (D_H / GQ) + gB0 + 0];

  int cur = 0;
  for (int g = 0; g < 16; ++g) {
    __syncthreads();

    if (g < 15) {
      const int kn = (g + 1) * 64;
      const int nb = cur ^ 1;
#pragma unroll
      for (int q = 0; q < 2; ++q) {
        int row = q * 64 + srow;
        gload_lds16(Aq + (long)(t0 + row) * PANW + kn + sswz,
                    &As[nb][row * 64 + ske]);
        gload_lds16(Bq + (long)(c0 + row) * D_H + kB0 + kn + sswz,
                    &Bs[nb][row * 64 + ske]);
      }
      if (tid < 128)      sxd[nb][tid] = Asx[(long)(t0 + tid) * (PANW / GQ) + (g + 1)];
      else if (tid < 256) wss[nb][tid - 128] = Bws[(long)(c0 + tid - 128) * (D_H / GQ) + gB0 + (g + 1)];
    }

    float sd[2][4];
#pragma unroll
    for (int m = 0; m < 2; ++m)
#pragma unroll
      for (int jj = 0; jj < 4; ++jj)
        sd[m][jj] = sxd[cur][wr * 32 + m * 16 + l4 * 4 + jj];
    float wd[4];
#pragma unroll
    for (int n = 0; n < 4; ++n)
      wd[n] = wss[cur][wc * 64 + n * 16 + l15];

    bf16x8 af[2][2], bfr[4][2];
#pragma unroll
    for (int m = 0; m < 2; ++m) {
      const int r = wr * 32 + m * 16 + l15;
      const unsigned short* base = &As[cur][r * 64];
      af[m][0] = *(const bf16x8*)(base + ((l4    ) ^ (r & 7)) * 8);
      af[m][1] = *(const bf16x8*)(base + ((l4 + 4) ^ (r & 7)) * 8);
    }
#pragma unroll
    for (int n = 0; n < 4; ++n) {
      const int r = wc * 64 + n * 16 + l15;
      const unsigned short* base = &Bs[cur][r * 64];
      bfr[n][0] = *(const bf16x8*)(base + ((l4    ) ^ (r & 7)) * 8);
      bfr[n][1] = *(const bf16x8*)(base + ((l4 + 4) ^ (r & 7)) * 8);
    }

#pragma unroll
    for (int m = 0; m < 2; ++m) {
#pragma unroll
      for (int n = 0; n < 4; ++n) {
        f32x4 t = {0.f, 0.f, 0.f, 0.f};
        t = __builtin_amdgcn_mfma_f32_16x16x32_bf16(af[m][0], bfr[n][0], t, 0, 0, 0);
        t = __builtin_amdgcn_mfma_f32_16x16x32_bf16(af[m][1], bfr[n][1], t, 0, 0, 0);
#pragma unroll
        for (int j = 0; j < 4; ++j)
          acc[m][n][j] = fmaf(t[j], sd[m][j] * wd[n], acc[m][n][j]);
      }
    }
    cur ^= 1;
  }

  if (last) {
    // stage xr2a rows / lu2 cols into reused LDS (fc1's proven pattern)
    __syncthreads();
    float* xr_lds = (float*)&As[0][0];    // [128][36]
    float* lu_lds = (float*)&Bs[0][0];    // [128][36]
    {
      const int row = tid >> 2;
      const int q4  = (tid & 3) * 8;
      const float4 a0 = *(const float4*)(xr2a + (size_t)(t0 + row) * R_L + q4);
      const float4 a1 = *(const float4*)(xr2a + (size_t)(t0 + row) * R_L + q4 + 4);
      *(float4*)&xr_lds[row * 36 + q4]     = a0;
      *(float4*)&xr_lds[row * 36 + q4 + 4] = a1;
      const float4 b0 = *(const float4*)(lu2 + (size_t)(c0 + row) * R_L + q4);
      const float4 b1v = *(const float4*)(lu2 + (size_t)(c0 + row) * R_L + q4 + 4);
      *(float4*)&lu_lds[row * 36 + q4]     = b0;
      *(float4*)&lu_lds[row * 36 + q4 + 4] = b1v;
    }
    __syncthreads();

    float bv[4];
    int colL[4];
#pragma unroll
    for (int n = 0; n < 4; ++n) {
      colL[n] = wc * 64 + n * 16 + l15;
      bv[n] = b2[c0 + colL[n]];
    }
#pragma unroll
    for (int m = 0; m < 2; ++m) {
#pragma unroll
      for (int j = 0; j < 4; ++j) {
        const int rloc = wr * 32 + m * 16 + l4 * 4 + j;
        const int trow = t0 + rloc;
        float lor[4] = {0.f, 0.f, 0.f, 0.f};
#pragma unroll
        for (int k = 0; k < 8; ++k) {
          const float4 xq = *(const float4*)&xr_lds[rloc * 36 + k * 4];
#pragma unroll
          for (int n = 0; n < 4; ++n) {
            const float4 lc = *(const float4*)&lu_lds[colL[n] * 36 + k * 4];
            lor[n] = fmaf(xq.x, lc.x, lor[n]);
            lor[n] = fmaf(xq.y, lc.y, lor[n]);
            lor[n] = fmaf(xq.z, lc.z, lor[n]);
            lor[n] = fmaf(xq.w, lc.w, lor[n]);
          }
        }
#pragma unroll
        for (int n = 0; n < 4; ++n) {
          size_t idx = (size_t)trow * D_IN + c0 + colL[n];
          Yout[idx] = Yout[idx] + acc[m][n][j] + lor[n] + bv[n];
        }
      }
    }
  } else {
#pragma unroll
    for (int m = 0; m < 2; ++m)
#pragma unroll
      for (int n = 0; n < 4; ++n) {
        int col = c0 + wc * 64 + n * 16 + l15;
#pragma unroll
        for (int j = 0; j < 4; ++j) {
          int trow = t0 + wr * 32 + m * 16 + l4 * 4 + j;
          size_t idx = (size_t)trow * D_IN + col;
          float v = acc[m][n][j];
          if (!first) v += Yout[idx];
          Yout[idx] = v;
        }
      }
  }
}

// ---------------- xr2 (+)= h_panel @ ld2^T (exact VALU f32) --------
__global__ __launch_bounds__(256)
void xr2_simple(const unsigned short* __restrict__ hp,  // [T][PANW] bf16
                const float* __restrict__ ld2,          // [32][D_H] f32 raw
                int c0base,
                float* __restrict__ xracc,              // [T][32] f32
                int first) {
  __shared__ unsigned short hs[8][PANW + 8];
  const int tid = threadIdx.x;
  const int t0 = blockIdx.x * 8;
#pragma unroll
  for (int q = 0; q < 4; ++q) {
    int v = tid + 256 * q;
    int row = v >> 7;
    int col = (v & 127) * 8;
    *(ushort8*)(&hs[row][col]) =
        *(const ushort8*)(hp + (size_t)(t0 + row) * PANW + col);
  }
  __syncthreads();
  const int tloc = tid & 7;
  const int r    = tid >> 3;
  const float* ldr = ld2 + (size_t)r * D_H + c0base;
  float sum = 0.f;
  for (int k8 = 0; k8 < PANW / 8; ++k8) {
    ushort8 hv = *(const ushort8*)(&hs[tloc][k8 * 8]);
    float4 w0 = *(const float4*)(ldr + k8 * 8);
    float4 w1 = *(const float4*)(ldr + k8 * 8 + 4);
    sum = fmaf(bf2f(hv[0]), w0.x, sum);
    sum = fmaf(bf2f(hv[1]), w0.y, sum);
    sum = fmaf(bf2f(hv[2]), w0.z, sum);
    sum = fmaf(bf2f(hv[3]), w0.w, sum);
    sum = fmaf(bf2f(hv[4]), w1.x, sum);
    sum = fmaf(bf2f(hv[5]), w1.y, sum);
    sum = fmaf(bf2f(hv[6]), w1.z, sum);
    sum = fmaf(bf2f(hv[7]), w1.w, sum);
  }
  size_t idx = (size_t)(t0 + tloc) * R_L + r;
  xracc[idx] = (first ? 0.f : xracc[idx]) + sum;
}

extern "C" void kernel_launch(void* const* d_in, const int* in_sizes, int n_in,
                              void* d_out, int out_size, void* d_ws, size_t ws_size,
                              hipStream_t stream) {
  const float* x       = (const float*)d_in[0];
  const int*   qw1     = (const int*)d_in[1];
  const float* ws1     = (const float*)d_in[2];
  const float* smooth1 = (const float*)d_in[3];
  const float* ld1     = (const float*)d_in[4];
  const float* lu1     = (const float*)d_in[5];
  const float* b1      = (const float*)d_in[6];
  const int*   qw2     = (const int*)d_in[7];
  const float* ws2     = (const float*)d_in[8];
  const float* smooth2 = (const float*)d_in[9];
  const float* ld2     = (const float*)d_in[10];
  const float* lu2     = (const float*)d_in[11];
  const float* b2      = (const float*)d_in[12];

  char* w = (char*)d_ws;
  size_t off = 0;
  auto take = [&](size_t bytes) {
    char* p = w + off;
    off = (off + bytes + 255) & ~(size_t)255;
    return p;
  };

  // Peak workspace ~= 117 MiB
  unsigned short* qw1b = (unsigned short*)take((size_t)D_H * D_IN * 2);      // 8 MB
  unsigned short* qw2b = (unsigned short*)take((size_t)D_IN * D_H * 2);      // 8 MB
  unsigned short* qx1  = (unsigned short*)take((size_t)T_TOK * D_IN * 2);    // 32 MB
  float*          sx1  = (float*)take((size_t)T_TOK * (D_IN / GQ) * 4);      // 1 MB
  float*          xr1f = (float*)take((size_t)T_TOK * R_L * 4);              // 2 MB
  unsigned short* hp   = (unsigned short*)take((size_t)T_TOK * PANW * 2);    // 32 MB
  unsigned short* qx2p = (unsigned short*)take((size_t)T_TOK * PANW * 2);    // 32 MB
  float*          sx2  = (float*)take((size_t)T_TOK * (PANW / GQ) * 4);      // 1 MB
  float*          xr2a = (float*)take((size_t)T_TOK * R_L * 4);              // 2 MB
  (void)ws_size; (void)in_sizes; (void)n_in; (void)out_size;

  convert_kernel<<<2048, 256, 0, stream>>>(qw1, qw2, qw1b, qw2b);
  prep1_kernel<<<T_TOK, 256, 0, stream>>>(x, smooth1, ld1, qx1, sx1, xr1f);

  for (int p = 0; p < NPANEL; ++p) {
    const int c0base = p * PANW;
    const int first = (p == 0), last = (p == NPANEL - 1);

    dim3 g1(PANW / 128, T_TOK / 128);
    gemm_fc1<<<g1, 512, 0, stream>>>(qx1, sx1, qw1b, ws1, xr1f, lu1, b1, smooth2,
                                     c0base, hp, qx2p, sx2);

    xr2_simple<<<T_TOK / 8, 256, 0, stream>>>(hp, ld2, c0base, xr2a, first);

    dim3 g2(D_IN / 128, T_TOK / 128);
    gemm_fc2<<<g2, 512, 0, stream>>>(qx2p, sx2, qw2b, c0base, ws2, p * (PANW / GQ),
                                     xr2a, lu2, b2, (float*)d_out, first, last);
  }
}

// Round 17
// 1204.309 us; speedup vs baseline: 1.1463x; 1.1463x over previous
//
#include <hip/hip_runtime.h>
#include <math.h>

#define T_TOK 16384
#define D_IN  1024
#define D_H   4096
#define GQ    64
#define R_L   32
#define NPANEL 4
#define PANW   (D_H / NPANEL)   // 1024 fc1-output cols per panel

typedef __attribute__((ext_vector_type(8))) __bf16 bf16x8;
typedef __attribute__((ext_vector_type(4))) float  f32x4;
typedef __attribute__((ext_vector_type(8))) unsigned short ushort8;

__device__ __forceinline__ unsigned short f2bf(float f) {
  union { float f; unsigned u; } v; v.f = f;
  unsigned u = v.u + 0x7FFFu + ((v.u >> 16) & 1u);
  return (unsigned short)(u >> 16);
}

__device__ __forceinline__ float bf2f(unsigned short h) {
  union { unsigned u; float f; } v; v.u = ((unsigned)h) << 16; return v.f;
}

__device__ __forceinline__ void gload_lds16(const unsigned short* g, unsigned short* l) {
  __builtin_amdgcn_global_load_lds(
      (const __attribute__((address_space(1))) unsigned int*)g,
      (__attribute__((address_space(3))) unsigned int*)l, 16, 0, 0);
}

// f32 tanh-GELU (h-path errors ~1e-7 only hit the cheap fc2 quantizer)
__device__ __forceinline__ float gelu_tanh(float v) {
  float u = 0.7978845608028654f * (v + 0.044715f * v * v * v);
  return 0.5f * v * (1.0f + tanhf(u));
}

// ---------------- K0: int4 weights -> bf16 (exact) ----------------
__global__ __launch_bounds__(256)
void convert_kernel(const int* __restrict__ qw1, const int* __restrict__ qw2,
                    unsigned short* __restrict__ qw1b, unsigned short* __restrict__ qw2b) {
  const size_t N1 = (size_t)D_H * D_IN;
  const size_t N2 = (size_t)D_IN * D_H;
  const size_t total = N1 + N2;
  for (size_t i = (size_t)blockIdx.x * 256 + threadIdx.x; i < total;
       i += (size_t)gridDim.x * 256) {
    if (i < N1) qw1b[i]    = f2bf((float)qw1[i]);
    else        qw2b[i-N1] = f2bf((float)qw2[i-N1]);
  }
}

// ---------------- K1: fc1 qdq in f64 (decisions MUST match f64 ref) ----------------
__global__ __launch_bounds__(256)
void prep1_kernel(const float* __restrict__ x, const float* __restrict__ smooth,
                  const float* __restrict__ ld,
                  unsigned short* __restrict__ qx, float* __restrict__ sx,
                  float* __restrict__ xrf) {
  __shared__ float xrow[D_IN];
  const int t = blockIdx.x;
  const int tid = threadIdx.x;
  float4 x4  = *(const float4*)(x + (size_t)t * D_IN + tid * 4);
  float4 sm4 = *(const float4*)(smooth + tid * 4);
  *(float4*)&xrow[tid * 4] = x4;
  double z0 = (double)x4.x / (double)sm4.x;
  double z1 = (double)x4.y / (double)sm4.y;
  double z2 = (double)x4.z / (double)sm4.z;
  double z3 = (double)x4.w / (double)sm4.w;
  double amax = fmax(fmax(fabs(z0), fabs(z1)), fmax(fabs(z2), fabs(z3)));
#pragma unroll
  for (int d = 1; d < 16; d <<= 1) amax = fmax(amax, __shfl_xor(amax, d, 16));
  double s = fmax(amax, 1e-6) / 7.0;
  double q0 = fmin(fmax(rint(z0 / s), -8.0), 7.0);
  double q1 = fmin(fmax(rint(z1 / s), -8.0), 7.0);
  double q2 = fmin(fmax(rint(z2 / s), -8.0), 7.0);
  double q3 = fmin(fmax(rint(z3 / s), -8.0), 7.0);
  ushort4 qu; qu.x = f2bf((float)q0); qu.y = f2bf((float)q1);
  qu.z = f2bf((float)q2); qu.w = f2bf((float)q3);
  *(ushort4*)(qx + (size_t)t * D_IN + tid * 4) = qu;
  if ((tid & 15) == 0) sx[(size_t)t * (D_IN / GQ) + (tid >> 4)] = (float)s;
  __syncthreads();
  // LoRA-down dot in f32: feeds the h-path only (budget 1e-4; f32 gives ~1e-6)
  const int w = tid >> 6, l = tid & 63;
#pragma unroll
  for (int rr = 0; rr < 8; ++rr) {
    int r = w * 8 + rr;
    const float* ldr = ld + (size_t)r * D_IN;
    float sum = 0.f;
#pragma unroll
    for (int k = 0; k < 16; ++k)
      sum = fmaf(xrow[l + 64 * k], ldr[l + 64 * k], sum);
#pragma unroll
    for (int d = 32; d >= 1; d >>= 1) sum += __shfl_xor(sum, d, 64);
    if (l == 0) xrf[(size_t)t * R_L + r] = sum;
  }
}

// ---------------- FC1: 256-thread wave=64x64 (the round-14-fc2-proven shape) ----
// Single-buffered linear LDS (33KB staging, 37KB peak) -> ~4 blocks/CU = 4
// independent barrier domains; cross-block overlap (m114) hides the drain.
// Epilogue xr/lu staged into overlaid LDS (stride 36), f32 lora+gelu+qdq.
__global__ __launch_bounds__(256, 2)
void gemm_fc1(const unsigned short* __restrict__ Aq,    // [T][1024] bf16 q
              const float* __restrict__ Asx,            // [T][16] f32
              const unsigned short* __restrict__ Bq,    // [4096][1024] bf16 q
              const float* __restrict__ Bws,            // [4096][16] f32
              const float* __restrict__ xrf,            // [T][32] f32
              const float* __restrict__ lu1,            // [4096][32] f32 raw
              const float* __restrict__ b1,             // [4096]
              const float* __restrict__ smooth2,        // [4096]
              int c0base,
              unsigned short* __restrict__ hb,          // [T][PANW] bf16
              unsigned short* __restrict__ qx2,         // [T][PANW] bf16
              float* __restrict__ sx2) {                // [T][16] f32 panel-local
  __shared__ __align__(16) char smem[36864];
  unsigned short* As = (unsigned short*)smem;           // 16384 B
  unsigned short* Bs = (unsigned short*)(smem + 16384); // 16384 B
  float* sxs = (float*)(smem + 32768);                  // 512 B
  float* wss = (float*)(smem + 33280);                  // 512 B
  const int tid = threadIdx.x;
  const int lane = tid & 63;
  const int wid = tid >> 6;
  const int wr = wid >> 1, wc = wid & 1;                // 2x2 waves of 64x64
  const int l15 = lane & 15, l4 = lane >> 4;
  // T1: bijective XCD-chunked remap (nwg = 8*128)
  const int lin = blockIdx.y * 8 + blockIdx.x;
  const int sw  = (lin & 7) * 128 + (lin >> 3);
  const int t0 = (sw >> 3) * 128;
  const int c0 = c0base + (sw & 7) * 128;

  f32x4 acc[4][4] = {};
  const int srow = tid >> 3;          // 0..31
  const int ske  = (tid & 7) * 8;

  for (int g = 0; g < 16; ++g) {
    const int kA = g * 64 + ske;
#pragma unroll
    for (int i = 0; i < 4; ++i) {
      int row = i * 32 + srow;
      gload_lds16(Aq + (long)(t0 + row) * D_IN + kA, As + row * 64 + ske);
      gload_lds16(Bq + (long)(c0 + row) * D_IN + kA, Bs + row * 64 + ske);
    }
    if (tid < 128) sxs[tid] = Asx[(long)(t0 + tid) * 16 + g];
    else           wss[tid - 128] = Bws[(long)(c0 + tid - 128) * 16 + g];
    __syncthreads();

    bf16x8 af[4][2], bfr[4][2];
#pragma unroll
    for (int m = 0; m < 4; ++m) {
      const unsigned short* base = As + (wr * 64 + m * 16 + l15) * 64 + l4 * 8;
      af[m][0] = *(const bf16x8*)(base);
      af[m][1] = *(const bf16x8*)(base + 32);
    }
#pragma unroll
    for (int n = 0; n < 4; ++n) {
      const unsigned short* base = Bs + (wc * 64 + n * 16 + l15) * 64 + l4 * 8;
      bfr[n][0] = *(const bf16x8*)(base);
      bfr[n][1] = *(const bf16x8*)(base + 32);
    }
    f32x4 rsv[4];
#pragma unroll
    for (int m = 0; m < 4; ++m) rsv[m] = *(const f32x4*)&sxs[wr * 64 + m * 16 + l4 * 4];
    float csv[4];
#pragma unroll
    for (int n = 0; n < 4; ++n) csv[n] = wss[wc * 64 + n * 16 + l15];

#pragma unroll
    for (int m = 0; m < 4; ++m) {
#pragma unroll
      for (int n = 0; n < 4; ++n) {
        f32x4 t = {0.f, 0.f, 0.f, 0.f};   // exact integer group-sum (|I|<=4096)
        t = __builtin_amdgcn_mfma_f32_16x16x32_bf16(af[m][0], bfr[n][0], t, 0, 0, 0);
        t = __builtin_amdgcn_mfma_f32_16x16x32_bf16(af[m][1], bfr[n][1], t, 0, 0, 0);
#pragma unroll
        for (int j = 0; j < 4; ++j)
          acc[m][n][j] = fmaf(t[j], rsv[m][j] * csv[n], acc[m][n][j]);
      }
    }
    __syncthreads();
  }

  // ---- stage epilogue operands into overlaid LDS (stride 36: 2-way max) ----
  float* xr_lds = (float*)smem;             // [128][36] f32 = 18432 B
  float* lu_lds = (float*)(smem + 18432);   // [128][36] f32
  {
    const int row = tid >> 1;               // 0..127
    const int q4  = (tid & 1) * 16;         // 0 or 16
#pragma unroll
    for (int h = 0; h < 4; ++h) {
      *(float4*)&xr_lds[row * 36 + q4 + h * 4] =
          *(const float4*)(xrf + (size_t)(t0 + row) * R_L + q4 + h * 4);
      *(float4*)&lu_lds[row * 36 + q4 + h * 4] =
          *(const float4*)(lu1 + (size_t)(c0 + row) * R_L + q4 + h * 4);
    }
  }
  __syncthreads();

  // ---- f32 epilogue: lora1 (LDS-fed dot) + b1 + gelu + f32 qdq ----
  float bv[4], rsmv[4];
  int colL[4];
#pragma unroll
  for (int n = 0; n < 4; ++n) {
    int col = c0 + wc * 64 + n * 16 + l15;
    colL[n] = wc * 64 + n * 16 + l15;
    bv[n] = b1[col];
    rsmv[n] = 1.0f / smooth2[col];
  }
  const int clocal0 = c0 - c0base;

#pragma unroll
  for (int m = 0; m < 4; ++m) {
#pragma unroll
    for (int j = 0; j < 4; ++j) {
      const int rloc = wr * 64 + m * 16 + l4 * 4 + j;
      const int trow = t0 + rloc;
      float lor[4] = {0.f, 0.f, 0.f, 0.f};
#pragma unroll
      for (int k = 0; k < 8; ++k) {
        const float4 xq = *(const float4*)&xr_lds[rloc * 36 + k * 4];
#pragma unroll
        for (int n = 0; n < 4; ++n) {
          const float4 lc = *(const float4*)&lu_lds[colL[n] * 36 + k * 4];
          lor[n] = fmaf(xq.x, lc.x, lor[n]);
          lor[n] = fmaf(xq.y, lc.y, lor[n]);
          lor[n] = fmaf(xq.z, lc.z, lor[n]);
          lor[n] = fmaf(xq.w, lc.w, lor[n]);
        }
      }
      float hv[4], z[4];
      float amax = 0.f;
#pragma unroll
      for (int n = 0; n < 4; ++n) {
        float v = acc[m][n][j] + lor[n] + bv[n];
        v = gelu_tanh(v);
        hv[n] = v;
        z[n] = v * rsmv[n];
        amax = fmaxf(amax, fabsf(z[n]));
      }
#pragma unroll
      for (int d = 1; d < 16; d <<= 1) amax = fmaxf(amax, __shfl_xor(amax, d, 16));
      float s = fmaxf(amax, 1e-6f) / 7.0f;
      float rs = 1.0f / s;
#pragma unroll
      for (int n = 0; n < 4; ++n) {
        int coll = clocal0 + wc * 64 + n * 16 + l15;
        hb[(size_t)trow * PANW + coll] = f2bf(hv[n]);
        float qv = fminf(fmaxf(rintf(z[n] * rs), -8.f), 7.f);
        qx2[(size_t)trow * PANW + coll] = f2bf(qv);
      }
      if (l15 == 0)
        sx2[(size_t)trow * (PANW / GQ) + ((clocal0 + wc * 64) >> 6)] = s;
    }
  }
}

// ---------------- FC2: round-14 proven 256-thread version (T1, single-buf) ----------
__global__ __launch_bounds__(256, 2)
void gemm_fc2(const unsigned short* __restrict__ Aq,    // [T][PANW] bf16 q
              const float* __restrict__ Asx,            // [T][16] f32
              const unsigned short* __restrict__ Bq,    // [1024][4096] bf16 q
              int kB0,
              const float* __restrict__ Bws,            // [1024][64] f32
              int gB0,
              float* __restrict__ Yout, int first) {
  __shared__ unsigned short As[128 * 64];
  __shared__ unsigned short Bs[128 * 64];
  __shared__ float sxs[128];
  __shared__ float wss[128];
  const int tid = threadIdx.x;
  const int lane = tid & 63;
  const int wid = tid >> 6;
  const int wr = wid >> 1, wc = wid & 1;
  const int l15 = lane & 15, l4 = lane >> 4;
  const int lin = blockIdx.y * 8 + blockIdx.x;
  const int sw  = (lin & 7) * 128 + (lin >> 3);
  const int t0 = (sw >> 3) * 128;
  const int c0 = (sw & 7) * 128;

  f32x4 acc[4][4] = {};
  const int srow = tid >> 3;
  const int ske = (tid & 7) * 8;

  for (int g = 0; g < 16; ++g) {
    const int kA = g * 64 + ske;
    const int kB = kB0 + kA;
#pragma unroll
    for (int i = 0; i < 4; ++i) {
      int row = i * 32 + srow;
      gload_lds16(Aq + (long)(t0 + row) * PANW + kA, As + row * 64 + ske);
      gload_lds16(Bq + (long)(c0 + row) * D_H + kB, Bs + row * 64 + ske);
    }
    if (tid < 128) sxs[tid] = Asx[(long)(t0 + tid) * (PANW / GQ) + g];
    else           wss[tid - 128] = Bws[(long)(c0 + tid - 128) * (D_H / GQ) + gB0 + g];
    __syncthreads();

    bf16x8 af[4][2], bfr[4][2];
#pragma unroll
    for (int m = 0; m < 4; ++m) {
      const unsigned short* base = As + (wr * 64 + m * 16 + l15) * 64 + l4 * 8;
      af[m][0] = *(const bf16x8*)(base);
      af[m][1] = *(const bf16x8*)(base + 32);
    }
#pragma unroll
    for (int n = 0; n < 4; ++n) {
      const unsigned short* base = Bs + (wc * 64 + n * 16 + l15) * 64 + l4 * 8;
      bfr[n][0] = *(const bf16x8*)(base);
      bfr[n][1] = *(const bf16x8*)(base + 32);
    }
    f32x4 rsv[4];
#pragma unroll
    for (int m = 0; m < 4; ++m) rsv[m] = *(const f32x4*)&sxs[wr * 64 + m * 16 + l4 * 4];
    float csv[4];
#pragma unroll
    for (int n = 0; n < 4; ++n) csv[n] = wss[wc * 64 + n * 16 + l15];

#pragma unroll
    for (int m = 0; m < 4; ++m) {
#pragma unroll
      for (int n = 0; n < 4; ++n) {
        f32x4 t = {0.f, 0.f, 0.f, 0.f};
        t = __builtin_amdgcn_mfma_f32_16x16x32_bf16(af[m][0], bfr[n][0], t, 0, 0, 0);
        t = __builtin_amdgcn_mfma_f32_16x16x32_bf16(af[m][1], bfr[n][1], t, 0, 0, 0);
#pragma unroll
        for (int j = 0; j < 4; ++j)
          acc[m][n][j] += t[j] * (rsv[m][j] * csv[n]);
      }
    }
    __syncthreads();
  }

#pragma unroll
  for (int m = 0; m < 4; ++m)
#pragma unroll
    for (int n = 0; n < 4; ++n) {
      int col = c0 + wc * 64 + n * 16 + l15;
#pragma unroll
      for (int j = 0; j < 4; ++j) {
        int trow = t0 + wr * 64 + m * 16 + l4 * 4 + j;
        size_t idx = (size_t)trow * D_IN + col;
        float v = acc[m][n][j];
        if (!first) v += Yout[idx];
        Yout[idx] = v;
      }
    }
}

// ---------------- xr2 (+)= h_panel @ ld2^T (exact VALU f32) --------
__global__ __launch_bounds__(256)
void xr2_simple(const unsigned short* __restrict__ hp,  // [T][PANW] bf16
                const float* __restrict__ ld2,          // [32][D_H] f32 raw
                int c0base,
                float* __restrict__ xracc,              // [T][32] f32
                int first) {
  __shared__ unsigned short hs[8][PANW + 8];
  const int tid = threadIdx.x;
  const int t0 = blockIdx.x * 8;
#pragma unroll
  for (int q = 0; q < 4; ++q) {
    int v = tid + 256 * q;
    int row = v >> 7;
    int col = (v & 127) * 8;
    *(ushort8*)(&hs[row][col]) =
        *(const ushort8*)(hp + (size_t)(t0 + row) * PANW + col);
  }
  __syncthreads();
  const int tloc = tid & 7;
  const int r    = tid >> 3;
  const float* ldr = ld2 + (size_t)r * D_H + c0base;
  float sum = 0.f;
  for (int k8 = 0; k8 < PANW / 8; ++k8) {
    ushort8 hv = *(const ushort8*)(&hs[tloc][k8 * 8]);
    float4 w0 = *(const float4*)(ldr + k8 * 8);
    float4 w1 = *(const float4*)(ldr + k8 * 8 + 4);
    sum = fmaf(bf2f(hv[0]), w0.x, sum);
    sum = fmaf(bf2f(hv[1]), w0.y, sum);
    sum = fmaf(bf2f(hv[2]), w0.z, sum);
    sum = fmaf(bf2f(hv[3]), w0.w, sum);
    sum = fmaf(bf2f(hv[4]), w1.x, sum);
    sum = fmaf(bf2f(hv[5]), w1.y, sum);
    sum = fmaf(bf2f(hv[6]), w1.z, sum);
    sum = fmaf(bf2f(hv[7]), w1.w, sum);
  }
  size_t idx = (size_t)(t0 + tloc) * R_L + r;
  xracc[idx] = (first ? 0.f : xracc[idx]) + sum;
}

// ---------------- finish: y += b2 + xr2 @ lu2^T ----------------
__global__ __launch_bounds__(256)
void finish_kernel(const float* __restrict__ xracc,
                   const float* __restrict__ lu2,
                   const float* __restrict__ b2,
                   float* __restrict__ Yout) {
  __shared__ float xls[16][R_L];
  const int tid = threadIdx.x;
  const int o   = blockIdx.x * 256 + tid;
  const int t0r = blockIdx.y * 16;
  for (int q = tid; q < 16 * R_L; q += 256)
    xls[q >> 5][q & 31] = xracc[(size_t)(t0r + (q >> 5)) * R_L + (q & 31)];
  float lr[R_L];
#pragma unroll
  for (int r = 0; r < R_L; ++r) lr[r] = lu2[(size_t)o * R_L + r];
  const float b2v = b2[o];
  __syncthreads();
#pragma unroll
  for (int i = 0; i < 16; ++i) {
    size_t idx = (size_t)(t0r + i) * D_IN + o;
    float v = Yout[idx] + b2v;
#pragma unroll
    for (int r = 0; r < R_L; ++r) v = fmaf(lr[r], xls[i][r], v);
    Yout[idx] = v;
  }
}

extern "C" void kernel_launch(void* const* d_in, const int* in_sizes, int n_in,
                              void* d_out, int out_size, void* d_ws, size_t ws_size,
                              hipStream_t stream) {
  const float* x       = (const float*)d_in[0];
  const int*   qw1     = (const int*)d_in[1];
  const float* ws1     = (const float*)d_in[2];
  const float* smooth1 = (const float*)d_in[3];
  const float* ld1     = (const float*)d_in[4];
  const float* lu1     = (const float*)d_in[5];
  const float* b1      = (const float*)d_in[6];
  const int*   qw2     = (const int*)d_in[7];
  const float* ws2     = (const float*)d_in[8];
  const float* smooth2 = (const float*)d_in[9];
  const float* ld2     = (const float*)d_in[10];
  const float* lu2     = (const float*)d_in[11];
  const float* b2      = (const float*)d_in[12];

  char* w = (char*)d_ws;
  size_t off = 0;
  auto take = [&](size_t bytes) {
    char* p = w + off;
    off = (off + bytes + 255) & ~(size_t)255;
    return p;
  };

  // Peak workspace ~= 117 MiB
  unsigned short* qw1b = (unsigned short*)take((size_t)D_H * D_IN * 2);      // 8 MB
  unsigned short* qw2b = (unsigned short*)take((size_t)D_IN * D_H * 2);      // 8 MB
  unsigned short* qx1  = (unsigned short*)take((size_t)T_TOK * D_IN * 2);    // 32 MB
  float*          sx1  = (float*)take((size_t)T_TOK * (D_IN / GQ) * 4);      // 1 MB
  float*          xr1f = (float*)take((size_t)T_TOK * R_L * 4);              // 2 MB
  unsigned short* hp   = (unsigned short*)take((size_t)T_TOK * PANW * 2);    // 32 MB
  unsigned short* qx2p = (unsigned short*)take((size_t)T_TOK * PANW * 2);    // 32 MB
  float*          sx2  = (float*)take((size_t)T_TOK * (PANW / GQ) * 4);      // 1 MB
  float*          xr2a = (float*)take((size_t)T_TOK * R_L * 4);              // 2 MB
  (void)ws_size; (void)in_sizes; (void)n_in; (void)out_size;

  convert_kernel<<<2048, 256, 0, stream>>>(qw1, qw2, qw1b, qw2b);
  prep1_kernel<<<T_TOK, 256, 0, stream>>>(x, smooth1, ld1, qx1, sx1, xr1f);

  for (int p = 0; p < NPANEL; ++p) {
    const int c0base = p * PANW;
    const int first = (p == 0);

    dim3 g1(PANW / 128, T_TOK / 128);
    gemm_fc1<<<g1, 256, 0, stream>>>(qx1, sx1, qw1b, ws1, xr1f, lu1, b1, smooth2,
                                     c0base, hp, qx2p, sx2);

    xr2_simple<<<T_TOK / 8, 256, 0, stream>>>(hp, ld2, c0base, xr2a, first);

    dim3 g2(D_IN / 128, T_TOK / 128);
    gemm_fc2<<<g2, 256, 0, stream>>>(qx2p, sx2, qw2b, c0base, ws2, p * (PANW / GQ),
                                     (float*)d_out, first);
  }

  dim3 gf(D_IN / 256, T_TOK / 16);
  finish_kernel<<<gf, 256, 0, stream>>>(xr2a, lu2, b2, (float*)d_out);
}

// Round 18
// 1132.915 us; speedup vs baseline: 1.2186x; 1.0630x over previous
//
#include <hip/hip_runtime.h>
#include <math.h>

#define T_TOK 16384
#define D_IN  1024
#define D_H   4096
#define GQ    64
#define R_L   32
#define NPANEL 4
#define PANW   (D_H / NPANEL)   // 1024 fc1-output cols per panel

typedef __attribute__((ext_vector_type(8))) __bf16 bf16x8;
typedef __attribute__((ext_vector_type(4))) float  f32x4;
typedef __attribute__((ext_vector_type(8))) unsigned short ushort8;

__device__ __forceinline__ unsigned short f2bf(float f) {
  union { float f; unsigned u; } v; v.f = f;
  unsigned u = v.u + 0x7FFFu + ((v.u >> 16) & 1u);
  return (unsigned short)(u >> 16);
}

__device__ __forceinline__ float bf2f(unsigned short h) {
  union { unsigned u; float f; } v; v.u = ((unsigned)h) << 16; return v.f;
}

// split v into bf16 hi + bf16 lo (hi = RNE(v); v-hi exact in f32; lo = RNE(v-hi))
__device__ __forceinline__ void split_bf(float v, unsigned short* hi, unsigned short* lo) {
  unsigned short h = f2bf(v);
  *hi = h;
  *lo = f2bf(v - bf2f(h));
}

__device__ __forceinline__ void gload_lds16(const unsigned short* g, unsigned short* l) {
  __builtin_amdgcn_global_load_lds(
      (const __attribute__((address_space(1))) unsigned int*)g,
      (__attribute__((address_space(3))) unsigned int*)l, 16, 0, 0);
}

// fast f32 tanh-GELU via hw exp: tanh(u) = 1 - 2/(e^{2u}+1); rel err ~1e-6,
// saturates correctly (e->inf => t=1; e->0 => t=-1). h-budget is 1e-4.
__device__ __forceinline__ float gelu_fast(float v) {
  float u = 0.7978845608028654f * (v + 0.044715f * v * v * v);
  float e = __expf(2.0f * u);
  float t = 1.0f - 2.0f / (e + 1.0f);
  return 0.5f * v * (1.0f + t);
}

// ---------------- K0: int4 weights -> bf16 (exact) + lu1 split-bf16 ----------------
__global__ __launch_bounds__(256)
void convert_kernel(const int* __restrict__ qw1, const int* __restrict__ qw2,
                    const float* __restrict__ lu1,
                    unsigned short* __restrict__ qw1b, unsigned short* __restrict__ qw2b,
                    unsigned short* __restrict__ lu1h, unsigned short* __restrict__ lu1l) {
  const size_t N1 = (size_t)D_H * D_IN;
  const size_t N2 = (size_t)D_IN * D_H;
  const size_t N3 = (size_t)D_H * R_L;
  const size_t total = N1 + N2 + N3;
  for (size_t i = (size_t)blockIdx.x * 256 + threadIdx.x; i < total;
       i += (size_t)gridDim.x * 256) {
    if (i < N1)         qw1b[i]    = f2bf((float)qw1[i]);
    else if (i < N1+N2) qw2b[i-N1] = f2bf((float)qw2[i-N1]);
    else {
      size_t j = i - N1 - N2;
      split_bf(lu1[j], &lu1h[j], &lu1l[j]);
    }
  }
}

// ---------------- K1: fc1 qdq in f64 (decisions MUST match f64 ref) ----------------
__global__ __launch_bounds__(256)
void prep1_kernel(const float* __restrict__ x, const float* __restrict__ smooth,
                  const float* __restrict__ ld,
                  unsigned short* __restrict__ qx, float* __restrict__ sx,
                  unsigned short* __restrict__ xrh, unsigned short* __restrict__ xrl) {
  __shared__ float xrow[D_IN];
  const int t = blockIdx.x;
  const int tid = threadIdx.x;
  float4 x4  = *(const float4*)(x + (size_t)t * D_IN + tid * 4);
  float4 sm4 = *(const float4*)(smooth + tid * 4);
  *(float4*)&xrow[tid * 4] = x4;
  double z0 = (double)x4.x / (double)sm4.x;
  double z1 = (double)x4.y / (double)sm4.y;
  double z2 = (double)x4.z / (double)sm4.z;
  double z3 = (double)x4.w / (double)sm4.w;
  double amax = fmax(fmax(fabs(z0), fabs(z1)), fmax(fabs(z2), fabs(z3)));
#pragma unroll
  for (int d = 1; d < 16; d <<= 1) amax = fmax(amax, __shfl_xor(amax, d, 16));
  double s = fmax(amax, 1e-6) / 7.0;
  double q0 = fmin(fmax(rint(z0 / s), -8.0), 7.0);
  double q1 = fmin(fmax(rint(z1 / s), -8.0), 7.0);
  double q2 = fmin(fmax(rint(z2 / s), -8.0), 7.0);
  double q3 = fmin(fmax(rint(z3 / s), -8.0), 7.0);
  ushort4 qu; qu.x = f2bf((float)q0); qu.y = f2bf((float)q1);
  qu.z = f2bf((float)q2); qu.w = f2bf((float)q3);
  *(ushort4*)(qx + (size_t)t * D_IN + tid * 4) = qu;
  if ((tid & 15) == 0) sx[(size_t)t * (D_IN / GQ) + (tid >> 4)] = (float)s;
  __syncthreads();
  // LoRA-down dot in f32 (h-path budget 1e-4); store split-bf16 for MFMA epilogue
  const int w = tid >> 6, l = tid & 63;
#pragma unroll
  for (int rr = 0; rr < 8; ++rr) {
    int r = w * 8 + rr;
    const float* ldr = ld + (size_t)r * D_IN;
    float sum = 0.f;
#pragma unroll
    for (int k = 0; k < 16; ++k)
      sum = fmaf(xrow[l + 64 * k], ldr[l + 64 * k], sum);
#pragma unroll
    for (int d = 32; d >= 1; d >>= 1) sum += __shfl_xor(sum, d, 64);
    if (l == 0) split_bf(sum, &xrh[(size_t)t * R_L + r], &xrl[(size_t)t * R_L + r]);
  }
}

// ---------------- FC1: 256-thread wave=64x64; lora via 3 split-bf16 MFMAs;
//                  fast-exp GELU; no epilogue LDS staging ----------------
__global__ __launch_bounds__(256, 2)
void gemm_fc1(const unsigned short* __restrict__ Aq,    // [T][1024] bf16 q
              const float* __restrict__ Asx,            // [T][16] f32
              const unsigned short* __restrict__ Bq,    // [4096][1024] bf16 q
              const float* __restrict__ Bws,            // [4096][16] f32
              const unsigned short* __restrict__ xrh,   // [T][32] bf16 hi
              const unsigned short* __restrict__ xrl,   // [T][32] bf16 lo
              const unsigned short* __restrict__ luh,   // [4096][32] bf16 hi
              const unsigned short* __restrict__ lul,   // [4096][32] bf16 lo
              const float* __restrict__ b1,             // [4096]
              const float* __restrict__ smooth2,        // [4096]
              int c0base,
              unsigned short* __restrict__ hb,          // [T][PANW] bf16
              unsigned short* __restrict__ qx2,         // [T][PANW] bf16
              float* __restrict__ sx2) {                // [T][16] f32 panel-local
  __shared__ unsigned short As[128 * 64];
  __shared__ unsigned short Bs[128 * 64];
  __shared__ float sxs[128];
  __shared__ float wss[128];
  const int tid = threadIdx.x;
  const int lane = tid & 63;
  const int wid = tid >> 6;
  const int wr = wid >> 1, wc = wid & 1;                // 2x2 waves of 64x64
  const int l15 = lane & 15, l4 = lane >> 4;
  // T1: bijective XCD-chunked remap (nwg = 8*128)
  const int lin = blockIdx.y * 8 + blockIdx.x;
  const int sw  = (lin & 7) * 128 + (lin >> 3);
  const int t0 = (sw >> 3) * 128;
  const int c0 = c0base + (sw & 7) * 128;

  f32x4 acc[4][4] = {};
  const int srow = tid >> 3;          // 0..31
  const int ske  = (tid & 7) * 8;

  for (int g = 0; g < 16; ++g) {
    const int kA = g * 64 + ske;
#pragma unroll
    for (int i = 0; i < 4; ++i) {
      int row = i * 32 + srow;
      gload_lds16(Aq + (long)(t0 + row) * D_IN + kA, As + row * 64 + ske);
      gload_lds16(Bq + (long)(c0 + row) * D_IN + kA, Bs + row * 64 + ske);
    }
    if (tid < 128) sxs[tid] = Asx[(long)(t0 + tid) * 16 + g];
    else           wss[tid - 128] = Bws[(long)(c0 + tid - 128) * 16 + g];
    __syncthreads();

    bf16x8 af[4][2], bfr[4][2];
#pragma unroll
    for (int m = 0; m < 4; ++m) {
      const unsigned short* base = As + (wr * 64 + m * 16 + l15) * 64 + l4 * 8;
      af[m][0] = *(const bf16x8*)(base);
      af[m][1] = *(const bf16x8*)(base + 32);
    }
#pragma unroll
    for (int n = 0; n < 4; ++n) {
      const unsigned short* base = Bs + (wc * 64 + n * 16 + l15) * 64 + l4 * 8;
      bfr[n][0] = *(const bf16x8*)(base);
      bfr[n][1] = *(const bf16x8*)(base + 32);
    }
    f32x4 rsv[4];
#pragma unroll
    for (int m = 0; m < 4; ++m) rsv[m] = *(const f32x4*)&sxs[wr * 64 + m * 16 + l4 * 4];
    float csv[4];
#pragma unroll
    for (int n = 0; n < 4; ++n) csv[n] = wss[wc * 64 + n * 16 + l15];

#pragma unroll
    for (int m = 0; m < 4; ++m) {
#pragma unroll
      for (int n = 0; n < 4; ++n) {
        f32x4 t = {0.f, 0.f, 0.f, 0.f};   // exact integer group-sum (|I|<=4096)
        t = __builtin_amdgcn_mfma_f32_16x16x32_bf16(af[m][0], bfr[n][0], t, 0, 0, 0);
        t = __builtin_amdgcn_mfma_f32_16x16x32_bf16(af[m][1], bfr[n][1], t, 0, 0, 0);
#pragma unroll
        for (int j = 0; j < 4; ++j)
          acc[m][n][j] = fmaf(t[j], rsv[m][j] * csv[n], acc[m][n][j]);
      }
    }
    __syncthreads();
  }

  // ---- lora1 via split-bf16 MFMA: acc += xr_hi*lu_hi + xr_hi*lu_lo + xr_lo*lu_hi ----
  // (same fragment geometry as the main loop: A row=l15, k=l4*8; err ~4e-6 << 1e-4)
  {
    bf16x8 lah[4], lal[4], lbh[4], lbl[4];
#pragma unroll
    for (int m = 0; m < 4; ++m) {
      size_t rb = (size_t)(t0 + wr * 64 + m * 16 + l15) * R_L + l4 * 8;
      lah[m] = *(const bf16x8*)(xrh + rb);
      lal[m] = *(const bf16x8*)(xrl + rb);
    }
#pragma unroll
    for (int n = 0; n < 4; ++n) {
      size_t rb = (size_t)(c0 + wc * 64 + n * 16 + l15) * R_L + l4 * 8;
      lbh[n] = *(const bf16x8*)(luh + rb);
      lbl[n] = *(const bf16x8*)(lul + rb);
    }
#pragma unroll
    for (int m = 0; m < 4; ++m)
#pragma unroll
      for (int n = 0; n < 4; ++n) {
        acc[m][n] = __builtin_amdgcn_mfma_f32_16x16x32_bf16(lah[m], lbh[n], acc[m][n], 0, 0, 0);
        acc[m][n] = __builtin_amdgcn_mfma_f32_16x16x32_bf16(lah[m], lbl[n], acc[m][n], 0, 0, 0);
        acc[m][n] = __builtin_amdgcn_mfma_f32_16x16x32_bf16(lal[m], lbh[n], acc[m][n], 0, 0, 0);
      }
  }

  // ---- f32 epilogue: + b1, fast GELU, f32 qdq ----
  float bv[4], rsmv[4];
#pragma unroll
  for (int n = 0; n < 4; ++n) {
    int col = c0 + wc * 64 + n * 16 + l15;
    bv[n] = b1[col];
    rsmv[n] = 1.0f / smooth2[col];
  }
  const int clocal0 = c0 - c0base;

#pragma unroll
  for (int m = 0; m < 4; ++m) {
#pragma unroll
    for (int j = 0; j < 4; ++j) {
      const int trow = t0 + wr * 64 + m * 16 + l4 * 4 + j;
      float hv[4], z[4];
      float amax = 0.f;
#pragma unroll
      for (int n = 0; n < 4; ++n) {
        float v = gelu_fast(acc[m][n][j] + bv[n]);
        hv[n] = v;
        z[n] = v * rsmv[n];
        amax = fmaxf(amax, fabsf(z[n]));
      }
#pragma unroll
      for (int d = 1; d < 16; d <<= 1) amax = fmaxf(amax, __shfl_xor(amax, d, 16));
      float s = fmaxf(amax, 1e-6f) / 7.0f;
      float rs = 1.0f / s;
#pragma unroll
      for (int n = 0; n < 4; ++n) {
        int coll = clocal0 + wc * 64 + n * 16 + l15;
        hb[(size_t)trow * PANW + coll] = f2bf(hv[n]);
        float qv = fminf(fmaxf(rintf(z[n] * rs), -8.f), 7.f);
        qx2[(size_t)trow * PANW + coll] = f2bf(qv);
      }
      if (l15 == 0)
        sx2[(size_t)trow * (PANW / GQ) + ((clocal0 + wc * 64) >> 6)] = s;
    }
  }
}

// ---------------- FC2: round-14 proven 256-thread version (T1, single-buf) ----------
__global__ __launch_bounds__(256, 2)
void gemm_fc2(const unsigned short* __restrict__ Aq,    // [T][PANW] bf16 q
              const float* __restrict__ Asx,            // [T][16] f32
              const unsigned short* __restrict__ Bq,    // [1024][4096] bf16 q
              int kB0,
              const float* __restrict__ Bws,            // [1024][64] f32
              int gB0,
              float* __restrict__ Yout, int first) {
  __shared__ unsigned short As[128 * 64];
  __shared__ unsigned short Bs[128 * 64];
  __shared__ float sxs[128];
  __shared__ float wss[128];
  const int tid = threadIdx.x;
  const int lane = tid & 63;
  const int wid = tid >> 6;
  const int wr = wid >> 1, wc = wid & 1;
  const int l15 = lane & 15, l4 = lane >> 4;
  const int lin = blockIdx.y * 8 + blockIdx.x;
  const int sw  = (lin & 7) * 128 + (lin >> 3);
  const int t0 = (sw >> 3) * 128;
  const int c0 = (sw & 7) * 128;

  f32x4 acc[4][4] = {};
  const int srow = tid >> 3;
  const int ske = (tid & 7) * 8;

  for (int g = 0; g < 16; ++g) {
    const int kA = g * 64 + ske;
    const int kB = kB0 + kA;
#pragma unroll
    for (int i = 0; i < 4; ++i) {
      int row = i * 32 + srow;
      gload_lds16(Aq + (long)(t0 + row) * PANW + kA, As + row * 64 + ske);
      gload_lds16(Bq + (long)(c0 + row) * D_H + kB, Bs + row * 64 + ske);
    }
    if (tid < 128) sxs[tid] = Asx[(long)(t0 + tid) * (PANW / GQ) + g];
    else           wss[tid - 128] = Bws[(long)(c0 + tid - 128) * (D_H / GQ) + gB0 + g];
    __syncthreads();

    bf16x8 af[4][2], bfr[4][2];
#pragma unroll
    for (int m = 0; m < 4; ++m) {
      const unsigned short* base = As + (wr * 64 + m * 16 + l15) * 64 + l4 * 8;
      af[m][0] = *(const bf16x8*)(base);
      af[m][1] = *(const bf16x8*)(base + 32);
    }
#pragma unroll
    for (int n = 0; n < 4; ++n) {
      const unsigned short* base = Bs + (wc * 64 + n * 16 + l15) * 64 + l4 * 8;
      bfr[n][0] = *(const bf16x8*)(base);
      bfr[n][1] = *(const bf16x8*)(base + 32);
    }
    f32x4 rsv[4];
#pragma unroll
    for (int m = 0; m < 4; ++m) rsv[m] = *(const f32x4*)&sxs[wr * 64 + m * 16 + l4 * 4];
    float csv[4];
#pragma unroll
    for (int n = 0; n < 4; ++n) csv[n] = wss[wc * 64 + n * 16 + l15];

#pragma unroll
    for (int m = 0; m < 4; ++m) {
#pragma unroll
      for (int n = 0; n < 4; ++n) {
        f32x4 t = {0.f, 0.f, 0.f, 0.f};
        t = __builtin_amdgcn_mfma_f32_16x16x32_bf16(af[m][0], bfr[n][0], t, 0, 0, 0);
        t = __builtin_amdgcn_mfma_f32_16x16x32_bf16(af[m][1], bfr[n][1], t, 0, 0, 0);
#pragma unroll
        for (int j = 0; j < 4; ++j)
          acc[m][n][j] += t[j] * (rsv[m][j] * csv[n]);
      }
    }
    __syncthreads();
  }

#pragma unroll
  for (int m = 0; m < 4; ++m)
#pragma unroll
    for (int n = 0; n < 4; ++n) {
      int col = c0 + wc * 64 + n * 16 + l15;
#pragma unroll
      for (int j = 0; j < 4; ++j) {
        int trow = t0 + wr * 64 + m * 16 + l4 * 4 + j;
        size_t idx = (size_t)trow * D_IN + col;
        float v = acc[m][n][j];
        if (!first) v += Yout[idx];
        Yout[idx] = v;
      }
    }
}

// ---------------- xr2 (+)= h_panel @ ld2^T (exact VALU f32) --------
__global__ __launch_bounds__(256)
void xr2_simple(const unsigned short* __restrict__ hp,  // [T][PANW] bf16
                const float* __restrict__ ld2,          // [32][D_H] f32 raw
                int c0base,
                float* __restrict__ xracc,              // [T][32] f32
                int first) {
  __shared__ unsigned short hs[8][PANW + 8];
  const int tid = threadIdx.x;
  const int t0 = blockIdx.x * 8;
#pragma unroll
  for (int q = 0; q < 4; ++q) {
    int v = tid + 256 * q;
    int row = v >> 7;
    int col = (v & 127) * 8;
    *(ushort8*)(&hs[row][col]) =
        *(const ushort8*)(hp + (size_t)(t0 + row) * PANW + col);
  }
  __syncthreads();
  const int tloc = tid & 7;
  const int r    = tid >> 3;
  const float* ldr = ld2 + (size_t)r * D_H + c0base;
  float sum = 0.f;
  for (int k8 = 0; k8 < PANW / 8; ++k8) {
    ushort8 hv = *(const ushort8*)(&hs[tloc][k8 * 8]);
    float4 w0 = *(const float4*)(ldr + k8 * 8);
    float4 w1 = *(const float4*)(ldr + k8 * 8 + 4);
    sum = fmaf(bf2f(hv[0]), w0.x, sum);
    sum = fmaf(bf2f(hv[1]), w0.y, sum);
    sum = fmaf(bf2f(hv[2]), w0.z, sum);
    sum = fmaf(bf2f(hv[3]), w0.w, sum);
    sum = fmaf(bf2f(hv[4]), w1.x, sum);
    sum = fmaf(bf2f(hv[5]), w1.y, sum);
    sum = fmaf(bf2f(hv[6]), w1.z, sum);
    sum = fmaf(bf2f(hv[7]), w1.w, sum);
  }
  size_t idx = (size_t)(t0 + tloc) * R_L + r;
  xracc[idx] = (first ? 0.f : xracc[idx]) + sum;
}

// ---------------- finish: y += b2 + xr2 @ lu2^T ----------------
__global__ __launch_bounds__(256)
void finish_kernel(const float* __restrict__ xracc,
                   const float* __restrict__ lu2,
                   const float* __restrict__ b2,
                   float* __restrict__ Yout) {
  __shared__ float xls[16][R_L];
  const int tid = threadIdx.x;
  const int o   = blockIdx.x * 256 + tid;
  const int t0r = blockIdx.y * 16;
  for (int q = tid; q < 16 * R_L; q += 256)
    xls[q >> 5][q & 31] = xracc[(size_t)(t0r + (q >> 5)) * R_L + (q & 31)];
  float lr[R_L];
#pragma unroll
  for (int r = 0; r < R_L; ++r) lr[r] = lu2[(size_t)o * R_L + r];
  const float b2v = b2[o];
  __syncthreads();
#pragma unroll
  for (int i = 0; i < 16; ++i) {
    size_t idx = (size_t)(t0r + i) * D_IN + o;
    float v = Yout[idx] + b2v;
#pragma unroll
    for (int r = 0; r < R_L; ++r) v = fmaf(lr[r], xls[i][r], v);
    Yout[idx] = v;
  }
}

extern "C" void kernel_launch(void* const* d_in, const int* in_sizes, int n_in,
                              void* d_out, int out_size, void* d_ws, size_t ws_size,
                              hipStream_t stream) {
  const float* x       = (const float*)d_in[0];
  const int*   qw1     = (const int*)d_in[1];
  const float* ws1     = (const float*)d_in[2];
  const float* smooth1 = (const float*)d_in[3];
  const float* ld1     = (const float*)d_in[4];
  const float* lu1     = (const float*)d_in[5];
  const float* b1      = (const float*)d_in[6];
  const int*   qw2     = (const int*)d_in[7];
  const float* ws2     = (const float*)d_in[8];
  const float* smooth2 = (const float*)d_in[9];
  const float* ld2     = (const float*)d_in[10];
  const float* lu2     = (const float*)d_in[11];
  const float* b2      = (const float*)d_in[12];

  char* w = (char*)d_ws;
  size_t off = 0;
  auto take = [&](size_t bytes) {
    char* p = w + off;
    off = (off + bytes + 255) & ~(size_t)255;
    return p;
  };

  // Peak workspace ~= 117 MiB
  unsigned short* qw1b = (unsigned short*)take((size_t)D_H * D_IN * 2);      // 8 MB
  unsigned short* qw2b = (unsigned short*)take((size_t)D_IN * D_H * 2);      // 8 MB
  unsigned short* lu1h = (unsigned short*)take((size_t)D_H * R_L * 2);       // 256 KB
  unsigned short* lu1l = (unsigned short*)take((size_t)D_H * R_L * 2);       // 256 KB
  unsigned short* qx1  = (unsigned short*)take((size_t)T_TOK * D_IN * 2);    // 32 MB
  float*          sx1  = (float*)take((size_t)T_TOK * (D_IN / GQ) * 4);      // 1 MB
  unsigned short* xr1h = (unsigned short*)take((size_t)T_TOK * R_L * 2);     // 1 MB
  unsigned short* xr1l = (unsigned short*)take((size_t)T_TOK * R_L * 2);     // 1 MB
  unsigned short* hp   = (unsigned short*)take((size_t)T_TOK * PANW * 2);    // 32 MB
  unsigned short* qx2p = (unsigned short*)take((size_t)T_TOK * PANW * 2);    // 32 MB
  float*          sx2  = (float*)take((size_t)T_TOK * (PANW / GQ) * 4);      // 1 MB
  float*          xr2a = (float*)take((size_t)T_TOK * R_L * 4);              // 2 MB
  (void)ws_size; (void)in_sizes; (void)n_in; (void)out_size;

  convert_kernel<<<2048, 256, 0, stream>>>(qw1, qw2, lu1, qw1b, qw2b, lu1h, lu1l);
  prep1_kernel<<<T_TOK, 256, 0, stream>>>(x, smooth1, ld1, qx1, sx1, xr1h, xr1l);

  for (int p = 0; p < NPANEL; ++p) {
    const int c0base = p * PANW;
    const int first = (p == 0);

    dim3 g1(PANW / 128, T_TOK / 128);
    gemm_fc1<<<g1, 256, 0, stream>>>(qx1, sx1, qw1b, ws1, xr1h, xr1l, lu1h, lu1l,
                                     b1, smooth2, c0base, hp, qx2p, sx2);

    xr2_simple<<<T_TOK / 8, 256, 0, stream>>>(hp, ld2, c0base, xr2a, first);

    dim3 g2(D_IN / 128, T_TOK / 128);
    gemm_fc2<<<g2, 256, 0, stream>>>(qx2p, sx2, qw2b, c0base, ws2, p * (PANW / GQ),
                                     (float*)d_out, first);
  }

  dim3 gf(D_IN / 256, T_TOK / 16);
  finish_kernel<<<gf, 256, 0, stream>>>(xr2a, lu2, b2, (float*)d_out);
}